// Round 11
// baseline (200.624 us; speedup 1.0000x reference)
//
#include <hip/hip_runtime.h>
#include <stdint.h>

typedef short short8 __attribute__((ext_vector_type(8)));
typedef float f32x4 __attribute__((ext_vector_type(4)));
typedef float f32x16 __attribute__((ext_vector_type(16)));
typedef unsigned int u32x4 __attribute__((ext_vector_type(4)));
typedef float float4e __attribute__((ext_vector_type(4)));
typedef unsigned short u16;

#define BB 4
#define SS 2048
#define DD 1024
#define HH 16
#define MM (BB*SS)   // 8192

// ---------- helpers ----------
__device__ __forceinline__ u16 f2bf(float f) {
    unsigned u = __float_as_uint(f);
    u += 0x7FFFu + ((u >> 16) & 1u);   // RTN-even
    return (u16)(u >> 16);
}
__device__ __forceinline__ float bf2f(u16 h) {
    return __uint_as_float(((unsigned)h) << 16);
}
__device__ __forceinline__ unsigned cvtpk(float a, float b) {
    unsigned r;
    asm("v_cvt_pk_bf16_f32 %0, %1, %2" : "=v"(r) : "v"(a), "v"(b));
    return r;
}
// async global->LDS, 16B per lane. dst must be wave-uniform base (HW adds lane*16).
__device__ __forceinline__ void gload16(const void* g, void* l) {
    __builtin_amdgcn_global_load_lds(
        (const __attribute__((address_space(1))) unsigned int*)(uintptr_t)g,
        (__attribute__((address_space(3))) unsigned int*)(unsigned)(uintptr_t)l,
        16, 0, 0);
}
__device__ __forceinline__ bool tens_is_bf(const u16* mref) { return mref[1] == 0xCE6Eu; }

// ---------- kernel 1: x -> bf16 ----------
__global__ __launch_bounds__(256) void cvt_x(const void* xin, u16* xb, const u16* mref) {
    bool isbf = tens_is_bf(mref);
    size_t i = (size_t)blockIdx.x * 256 + threadIdx.x;   // handles 8 elements
    if (isbf) {
        ((u32x4*)xb)[i] = ((const u32x4*)xin)[i];
    } else {
        const float4e* src = (const float4e*)xin;
        float4e a = src[2*i], b = src[2*i+1];
        u32x4 o;
        o[0] = (unsigned)f2bf(a[0]) | ((unsigned)f2bf(a[1]) << 16);
        o[1] = (unsigned)f2bf(a[2]) | ((unsigned)f2bf(a[3]) << 16);
        o[2] = (unsigned)f2bf(b[0]) | ((unsigned)f2bf(b[1]) << 16);
        o[3] = (unsigned)f2bf(b[2]) | ((unsigned)f2bf(b[3]) << 16);
        ((u32x4*)xb)[i] = o;
    }
}

// ---------- kernel 2: weights -> bf16 W^T [N][K] ----------
__global__ __launch_bounds__(256) void trw(const void* w0, const void* w1, const void* w2, const void* w3,
                                           u16* wt, const u16* mref) {
    bool isbf = tens_is_bf(mref);
    const void* w = (blockIdx.z == 0) ? w0 : (blockIdx.z == 1) ? w1 : (blockIdx.z == 2) ? w2 : w3;
    u16* out = wt + (size_t)blockIdx.z * (DD*DD);
    __shared__ float t[32][33];
    int tx = threadIdx.x & 31, ty = threadIdx.x >> 5;    // ty 0..7
    int n0 = blockIdx.x * 32, k0 = blockIdx.y * 32;
#pragma unroll
    for (int i = 0; i < 4; ++i) {
        int k = k0 + ty*4 + i;
        float v = isbf ? bf2f(((const u16*)w)[(size_t)k*DD + n0 + tx])
                       : ((const float*)w)[(size_t)k*DD + n0 + tx];
        t[ty*4 + i][tx] = v;
    }
    __syncthreads();
#pragma unroll
    for (int i = 0; i < 4; ++i)
        out[(size_t)(n0 + ty*4 + i)*DD + k0 + tx] = f2bf(t[tx][ty*4 + i]);
}

// ---------- kernel 3: 128x64 GEMM, BK=32 — 4 blocks/CU (occupancy fix for 2-blk/CU 128^2) ----------
// Same proven swizzle family as R3's kernel; only BN halves (ni<2, B stage = 1 chunk/thread).
// MODE 1: merged QKV via blockIdx.z (z=0 Q RoPE*0.125, z=1 K RoPE, z=2 V^T). Dispatch order
//         (x fastest, z slowest) == the 3 separate launches, minus 2 inter-launch drains.
// MODE 3: final projection, out f32 or bf16 per runtime flag.
template<int MODE>
__global__ __launch_bounds__(256) void gemm64(const u16* __restrict__ A, const u16* __restrict__ wt,
                                              u16* outQ, u16* outK, u16* outVT, void* Cout,
                                              const void* fcos, const void* fsin,
                                              const u16* mref) {
    __shared__ __align__(16) unsigned char smem[24576];   // 2 bufs x (8KB A + 4KB B)
    int tid = threadIdx.x;
    int w = tid >> 6, l = tid & 63, lo = l & 15, hi = l >> 4;
    int wm = w >> 1, wn = w & 1;
    int m0 = blockIdx.x * 128, n0 = blockIdx.y * 64;
    int wi = (MODE == 1) ? (int)blockIdx.z : 3;
    const u16* Bt = (MODE == 1) ? wt + (size_t)wi * (DD*DD) : wt;

    f32x4 acc[4][2] = {};

    auto stage = [&](int buf, int t) {
        int k0 = t * 32;
        // A: 128 rows x 64B, 512 chunks (2/thread)
#pragma unroll
        for (int i = 0; i < 2; ++i) {
            int idx = i*256 + tid;
            int row = idx >> 2, inb = (idx & 3) * 16;
            int sw  = inb ^ ((row & 3) << 4);
            gload16((const char*)A + ((size_t)(m0 + row)*DD + k0)*2 + sw,
                    smem + buf*12288 + (i*256 + (tid & ~63))*16);
        }
        // B: 64 rows x 64B, 256 chunks (1/thread)
        {
            int row = tid >> 2, inb = (tid & 3) * 16;
            int sw  = inb ^ ((row & 3) << 4);
            gload16((const char*)Bt + ((size_t)(n0 + row)*DD + k0)*2 + sw,
                    smem + buf*12288 + 8192 + (tid & ~63)*16);
        }
    };

    stage(0, 0);
    __syncthreads();
    int cur = 0;
    const int NT = DD / 32;   // 32
    for (int t = 0; t < NT; ++t) {
        if (t + 1 < NT) stage(cur ^ 1, t + 1);
        const char* Ab = (const char*)(smem + cur*12288);
        const char* Bb = Ab + 8192;
        short8 af[4], bfr[2];
#pragma unroll
        for (int mi = 0; mi < 4; ++mi) {
            int r = wm*64 + mi*16 + lo;
            af[mi] = *(const short8*)(Ab + r*64 + ((hi*16) ^ ((r & 3) << 4)));
        }
#pragma unroll
        for (int ni = 0; ni < 2; ++ni) {
            int r = wn*32 + ni*16 + lo;
            bfr[ni] = *(const short8*)(Bb + r*64 + ((hi*16) ^ ((r & 3) << 4)));
        }
        __builtin_amdgcn_s_setprio(1);
#pragma unroll
        for (int mi = 0; mi < 4; ++mi)
#pragma unroll
            for (int ni = 0; ni < 2; ++ni)
                acc[mi][ni] = __builtin_amdgcn_mfma_f32_16x16x32_bf16(af[mi], bfr[ni], acc[mi][ni], 0, 0, 0);
        __builtin_amdgcn_s_setprio(0);
        __syncthreads();
        cur ^= 1;
    }

    if (MODE == 1 && wi == 2) {
        // V: per-wave transpose (32 d x 64 s) via LDS -> V^T [B,H,HD,S]
        __syncthreads();
        u16* vs = (u16*)smem + w * (32*72);   // [32 d][72 s] per wave, 18KB total
#pragma unroll
        for (int ni = 0; ni < 2; ++ni) {
            int d = ni*16 + lo;               // 0..31 within wave
#pragma unroll
            for (int mi = 0; mi < 4; ++mi)
#pragma unroll
                for (int rr = 0; rr < 2; ++rr) {
                    unsigned pk = (unsigned)f2bf(acc[mi][ni][2*rr]) | ((unsigned)f2bf(acc[mi][ni][2*rr+1]) << 16);
                    *(unsigned*)(vs + d*72 + mi*16 + hi*4 + rr*2) = pk;
                }
        }
        asm volatile("s_waitcnt lgkmcnt(0)" ::: "memory");
        int srow0 = m0 + wm*64;
        int bq = srow0 >> 11;
        int s_base = srow0 & (SS-1);
        int h = n0 >> 6;                      // BN=64: block covers exactly one head
#pragma unroll
        for (int p = 0; p < 4; ++p) {
            int idx = p*64 + l;
            int row = idx >> 3, ch = idx & 7; // row 0..31, ch 0..7
            short8 vv = *(const short8*)(vs + row*72 + ch*8);
            int d = wn*32 + row;
            *(short8*)(outVT + (((size_t)bq*HH + h)*64 + d)*SS + s_base + ch*8) = vv;
        }
    } else if (MODE == 1) {
        // Q/K: RoPE + (Q-only) scale + write [B,H,S,HD]
        bool fbf = (((const u16*)fcos)[0] == 0x3F80u);   // freqs dtype self-detect
        u16* outp = wi ? outK : outQ;
        float oscale = wi ? 1.0f : 0.125f;
#pragma unroll
        for (int mi = 0; mi < 4; ++mi)
#pragma unroll
            for (int ni = 0; ni < 2; ++ni)
#pragma unroll
                for (int r = 0; r < 4; ++r) {
                    int gm = m0 + wm*64 + mi*16 + hi*4 + r;
                    int gc = n0 + wn*32 + ni*16 + lo;
                    float v  = acc[mi][ni][r];
                    float vp = __shfl_xor(v, 1);
                    int s = gm & (SS-1), d = gc & 63, i2 = d >> 1;
                    float c, sn;
                    if (fbf) { c = bf2f(((const u16*)fcos)[s*32 + i2]); sn = bf2f(((const u16*)fsin)[s*32 + i2]); }
                    else     { c = ((const float*)fcos)[s*32 + i2];     sn = ((const float*)fsin)[s*32 + i2]; }
                    float o = (gc & 1) ? (vp*sn + v*c) : (v*c - vp*sn);
                    o *= oscale;
                    int b = gm >> 11, h = gc >> 6;
                    outp[((((size_t)b*HH + h)*SS + s) << 6) + d] = f2bf(o);
                }
    } else {
        bool isbf = tens_is_bf(mref);
#pragma unroll
        for (int mi = 0; mi < 4; ++mi)
#pragma unroll
            for (int ni = 0; ni < 2; ++ni)
#pragma unroll
                for (int r = 0; r < 4; ++r) {
                    int gm = m0 + wm*64 + mi*16 + hi*4 + r;
                    int gc = n0 + wn*32 + ni*16 + lo;
                    float v = acc[mi][ni][r];
                    if (isbf) ((u16*)Cout)[(size_t)gm*DD + gc] = f2bf(v);
                    else      ((float*)Cout)[(size_t)gm*DD + gc] = v;
                }
    }
}

// ---------- kernel 4: causal flash attention v3 (measured best, byte-identical to R10) ----------
__global__ __launch_bounds__(256) void attn(const u16* __restrict__ Q, const u16* __restrict__ K,
                                            const u16* __restrict__ VT, u16* __restrict__ AO) {
    __shared__ __align__(16) u16 Kl[2][64*64];   // 8KB per buffer: 64 kv-rows x 128B
    __shared__ __align__(16) u16 Vl[2][64*64];   // 8KB per buffer: 64 d-rows x 128B
    int bh = blockIdx.x;
    int qt = (gridDim.y - 1) - blockIdx.y;          // longest first
    int tid = threadIdx.x, w = tid >> 6, l = tid & 63;
    int l31 = l & 31, hi5 = l >> 5;
    const u16* Qb = Q  + (size_t)bh * SS * 64;
    const u16* Kb = K  + (size_t)bh * SS * 64;
    const u16* Vb = VT + (size_t)bh * 64 * SS;
    int q0w = qt*128 + w*32;                         // wave's first q-row
    int q   = q0w + l31;                             // this lane-pair's q-row

    short8 qf[4];
#pragma unroll
    for (int kc = 0; kc < 4; ++kc)
        qf[kc] = *(const short8*)(Qb + (size_t)q*64 + kc*16 + hi5*8);

    f32x16 oacc[2] = {};     // O^T frags: col=q, rows d (dt*32 + pattern)
    float m_ = -1e30f, l_ = 0.f;

    auto stage = [&](int buf, int kt) {
        const char* Kt = (const char*)(Kb + (size_t)kt*64*64);
        const char* Vt = (const char*)Vb + (size_t)kt*128;
#pragma unroll
        for (int i = 0; i < 2; ++i) {
            int idx = i*256 + tid;
            int row = idx >> 3, inb = (idx & 7) * 16;   // 128B rows
            int sw = inb ^ ((row & 7) << 4);
            gload16(Kt + row*128 + sw,            (char*)Kl[buf] + (i*256 + (tid & ~63))*16);
            gload16(Vt + (size_t)row*(SS*2) + sw, (char*)Vl[buf] + (i*256 + (tid & ~63))*16);
        }
    };

    int nkt = 2*qt + 2;
    stage(0, 0);
    __syncthreads();
    int cur = 0;

    for (int kt = 0; kt < nkt; ++kt) {
        if (kt + 1 < nkt) stage(cur ^ 1, kt + 1);    // prefetch overlaps compute

        if (kt*64 <= q0w + 31) {                     // wave-uniform causal skip
            f32x16 sc[2] = {};
            __builtin_amdgcn_s_setprio(1);
#pragma unroll
            for (int kvt = 0; kvt < 2; ++kvt) {
                short8 kf[4];
#pragma unroll
                for (int kc = 0; kc < 4; ++kc) {
                    int row = kvt*32 + l31;
                    int ib = kc*32 + hi5*16;
                    kf[kc] = *(const short8*)((const char*)Kl[cur] + row*128 + (ib ^ ((row & 7) << 4)));
                }
#pragma unroll
                for (int kc = 0; kc < 4; ++kc)
                    sc[kvt] = __builtin_amdgcn_mfma_f32_32x32x16_bf16(kf[kc], qf[kc], sc[kvt], 0, 0, 0);
            }
            __builtin_amdgcn_s_setprio(0);

            if (kt*64 + 63 > q0w) {
#pragma unroll
                for (int kvt = 0; kvt < 2; ++kvt)
#pragma unroll
                    for (int rg = 0; rg < 16; ++rg) {
                        int kv = kt*64 + kvt*32 + (rg & 3) + 8*(rg >> 2) + 4*hi5;
                        if (kv > q) sc[kvt][rg] = -1e9f;
                    }
            }

            float mx = -1e30f;
#pragma unroll
            for (int kvt = 0; kvt < 2; ++kvt)
#pragma unroll
                for (int rg = 0; rg < 16; ++rg) mx = fmaxf(mx, sc[kvt][rg]);
            mx = fmaxf(mx, __shfl_xor(mx, 32));
            float mn = fmaxf(m_, mx);
            float al = __expf(m_ - mn);
            float rs = 0.f;
#pragma unroll
            for (int kvt = 0; kvt < 2; ++kvt)
#pragma unroll
                for (int rg = 0; rg < 16; ++rg) {
                    float p = __expf(sc[kvt][rg] - mn);
                    sc[kvt][rg] = p;
                    rs += p;
                }
            rs += __shfl_xor(rs, 32);
            m_ = mn;
            l_ = l_ * al + rs;
#pragma unroll
            for (int dt = 0; dt < 2; ++dt)
#pragma unroll
                for (int rg = 0; rg < 16; ++rg) oacc[dt][rg] *= al;

            short8 pa[4];
#pragma unroll
            for (int kc = 0; kc < 4; ++kc) {
                const int kvt = kc >> 1;
                const int base = (kc & 1) * 8;
                unsigned A0 = cvtpk(sc[kvt][base + 0], sc[kvt][base + 1]);
                unsigned A1 = cvtpk(sc[kvt][base + 2], sc[kvt][base + 3]);
                unsigned B0 = cvtpk(sc[kvt][base + 4], sc[kvt][base + 5]);
                unsigned B1 = cvtpk(sc[kvt][base + 6], sc[kvt][base + 7]);
                asm("v_permlane32_swap_b32 %0, %1" : "+v"(A0), "+v"(B0));
                asm("v_permlane32_swap_b32 %0, %1" : "+v"(A1), "+v"(B1));
                u32x4 pk; pk[0] = A0; pk[1] = A1; pk[2] = B0; pk[3] = B1;
                pa[kc] = __builtin_bit_cast(short8, pk);
            }

            __builtin_amdgcn_s_setprio(1);
#pragma unroll
            for (int dt = 0; dt < 2; ++dt) {
                short8 vf[4];
#pragma unroll
                for (int kc = 0; kc < 4; ++kc) {
                    int row = dt*32 + l31;
                    int ib = kc*32 + hi5*16;
                    vf[kc] = *(const short8*)((const char*)Vl[cur] + row*128 + (ib ^ ((row & 7) << 4)));
                }
#pragma unroll
                for (int kc = 0; kc < 4; ++kc)
                    oacc[dt] = __builtin_amdgcn_mfma_f32_32x32x16_bf16(vf[kc], pa[kc], oacc[dt], 0, 0, 0);
            }
            __builtin_amdgcn_s_setprio(0);
        }

        __syncthreads();     // buffer handoff; drains prefetch vmcnt
        cur ^= 1;
    }

    int b = bh >> 4, h = bh & 15;
    float inv = 1.0f / l_;
    u16* aor = AO + (size_t)(b*SS + q)*DD + h*64;
#pragma unroll
    for (int dt = 0; dt < 2; ++dt)
#pragma unroll
        for (int j = 0; j < 8; ++j) {
            int r0 = 2*j, r1 = 2*j + 1;
            int d = dt*32 + (r0 & 3) + 8*(r0 >> 2) + 4*hi5;
            unsigned pk = (unsigned)f2bf(oacc[dt][r0] * inv) | ((unsigned)f2bf(oacc[dt][r1] * inv) << 16);
            *(unsigned*)(aor + d) = pk;
        }
}

// ---------- launch ----------
extern "C" void kernel_launch(void* const* d_in, const int* in_sizes, int n_in,
                              void* d_out, int out_size, void* d_ws, size_t ws_size,
                              hipStream_t stream) {
    const void* x    = d_in[0];
    const void* fcos = d_in[1];
    const void* fsin = d_in[2];
    const u16*  mref = (const u16*)d_in[3];
    const void* wq   = d_in[4];
    const void* wk   = d_in[5];
    const void* wv   = d_in[6];
    const void* wo   = d_in[7];

    u16* ws = (u16*)d_ws;
    const size_t XB = (size_t)MM * DD;     // 8,388,608
    const size_t WT = (size_t)DD * DD;     // 1,048,576
    u16* xb  = ws;                 // x bf16 ; later aliased as attention output
    u16* wt  = ws + XB;            // 4 transposed weights (wq,wk,wv,wo contiguous)
    u16* qb  = ws + XB + 4*WT;
    u16* kb  = qb + XB;
    u16* vtb = kb + XB;

    cvt_x<<<4096, 256, 0, stream>>>(x, xb, mref);
    trw<<<dim3(32, 32, 4), 256, 0, stream>>>(wq, wk, wv, wo, wt, mref);
    // merged QKV: 128x64 tiles, grid (64,16,3) = 3072 blocks (z slowest => same order as 3 launches)
    gemm64<1><<<dim3(64, 16, 3), 256, 0, stream>>>(xb, wt, qb, kb, vtb, nullptr, fcos, fsin, mref);
    attn<<<dim3(64, 16), 256, 0, stream>>>(qb, kb, vtb, xb);   // AO aliases xb (safe: stream-ordered)
    // projection: 128x64 tiles, 1024 blocks
    gemm64<3><<<dim3(64, 16), 256, 0, stream>>>(xb, wt + 3*WT, nullptr, nullptr, nullptr, d_out, fcos, fsin, mref);
}

// Round 12
// 194.886 us; speedup vs baseline: 1.0294x; 1.0294x over previous
//
#include <hip/hip_runtime.h>
#include <stdint.h>

typedef short short8 __attribute__((ext_vector_type(8)));
typedef float f32x4 __attribute__((ext_vector_type(4)));
typedef float f32x16 __attribute__((ext_vector_type(16)));
typedef unsigned int u32x4 __attribute__((ext_vector_type(4)));
typedef float float4e __attribute__((ext_vector_type(4)));
typedef unsigned short u16;

#define BB 4
#define SS 2048
#define DD 1024
#define HH 16
#define MM (BB*SS)   // 8192

// ---------- helpers ----------
__device__ __forceinline__ u16 f2bf(float f) {
    unsigned u = __float_as_uint(f);
    u += 0x7FFFu + ((u >> 16) & 1u);   // RTN-even
    return (u16)(u >> 16);
}
__device__ __forceinline__ float bf2f(u16 h) {
    return __uint_as_float(((unsigned)h) << 16);
}
__device__ __forceinline__ unsigned cvtpk(float a, float b) {
    unsigned r;
    asm("v_cvt_pk_bf16_f32 %0, %1, %2" : "=v"(r) : "v"(a), "v"(b));
    return r;
}
// async global->LDS, 16B per lane. dst must be wave-uniform base (HW adds lane*16).
__device__ __forceinline__ void gload16(const void* g, void* l) {
    __builtin_amdgcn_global_load_lds(
        (const __attribute__((address_space(1))) unsigned int*)(uintptr_t)g,
        (__attribute__((address_space(3))) unsigned int*)(unsigned)(uintptr_t)l,
        16, 0, 0);
}
__device__ __forceinline__ bool tens_is_bf(const u16* mref) { return mref[1] == 0xCE6Eu; }

// ---------- kernel 1: x -> bf16 ----------
__global__ __launch_bounds__(256) void cvt_x(const void* xin, u16* xb, const u16* mref) {
    bool isbf = tens_is_bf(mref);
    size_t i = (size_t)blockIdx.x * 256 + threadIdx.x;   // handles 8 elements
    if (isbf) {
        ((u32x4*)xb)[i] = ((const u32x4*)xin)[i];
    } else {
        const float4e* src = (const float4e*)xin;
        float4e a = src[2*i], b = src[2*i+1];
        u32x4 o;
        o[0] = (unsigned)f2bf(a[0]) | ((unsigned)f2bf(a[1]) << 16);
        o[1] = (unsigned)f2bf(a[2]) | ((unsigned)f2bf(a[3]) << 16);
        o[2] = (unsigned)f2bf(b[0]) | ((unsigned)f2bf(b[1]) << 16);
        o[3] = (unsigned)f2bf(b[2]) | ((unsigned)f2bf(b[3]) << 16);
        ((u32x4*)xb)[i] = o;
    }
}

// ---------- kernel 2: weights -> bf16 W^T [N][K] ----------
__global__ __launch_bounds__(256) void trw(const void* w0, const void* w1, const void* w2, const void* w3,
                                           u16* wt, const u16* mref) {
    bool isbf = tens_is_bf(mref);
    const void* w = (blockIdx.z == 0) ? w0 : (blockIdx.z == 1) ? w1 : (blockIdx.z == 2) ? w2 : w3;
    u16* out = wt + (size_t)blockIdx.z * (DD*DD);
    __shared__ float t[32][33];
    int tx = threadIdx.x & 31, ty = threadIdx.x >> 5;    // ty 0..7
    int n0 = blockIdx.x * 32, k0 = blockIdx.y * 32;
#pragma unroll
    for (int i = 0; i < 4; ++i) {
        int k = k0 + ty*4 + i;
        float v = isbf ? bf2f(((const u16*)w)[(size_t)k*DD + n0 + tx])
                       : ((const float*)w)[(size_t)k*DD + n0 + tx];
        t[ty*4 + i][tx] = v;
    }
    __syncthreads();
#pragma unroll
    for (int i = 0; i < 4; ++i)
        out[(size_t)(n0 + ty*4 + i)*DD + k0 + tx] = f2bf(t[tx][ty*4 + i]);
}

// ---------- kernel 3: 128x128 GEMM, A[M][K] bf16 row-major, Bt[N][K] bf16 row-major ----------
// MODE 0: RoPE epilogue (scaled by oscale), out u16 [B,H,S,HD]   (Q and K launches)
// MODE 2: out u16 V^T [B,H,HD,S]  (per-wave LDS transpose epilogue)
// MODE 3: final: out f32 or bf16 [M][D] per runtime flag
template<int MODE>
__global__ __launch_bounds__(256) void gemm128(const u16* __restrict__ A, const u16* __restrict__ Bt,
                                               void* Cout, const void* fcos, const void* fsin,
                                               const u16* mref, float oscale) {
    constexpr int SMEMB = (MODE == 2) ? 36864 : 32768;
    __shared__ __align__(16) unsigned char smem[SMEMB];
    int tid = threadIdx.x;
    int w = tid >> 6, l = tid & 63, lo = l & 15, hi = l >> 4;
    int wm = w >> 1, wn = w & 1;
    int m0 = blockIdx.x * 128, n0 = blockIdx.y * 128;

    f32x4 acc[4][4] = {};

    auto stage = [&](int buf, int t) {
        int k0 = t * 32;
#pragma unroll
        for (int i = 0; i < 2; ++i) {
            int o = (i*256 + tid) * 16;          // 0..8191 linear byte offset in tile
            int row = o >> 6, inb = o & 63;      // 64B per row (32 bf16)
            int sw  = inb ^ ((row & 3) << 4);    // XOR swizzle, both-sides
            gload16((const char*)A + ((size_t)(m0 + row)*DD + k0)*2 + sw,
                    smem + buf*16384 + (i*256 + (tid & ~63))*16);
            gload16((const char*)Bt + ((size_t)(n0 + row)*DD + k0)*2 + sw,
                    smem + buf*16384 + 8192 + (i*256 + (tid & ~63))*16);
        }
    };

    stage(0, 0);
    __syncthreads();
    int cur = 0;
    const int NT = DD / 32;   // 32
    for (int t = 0; t < NT; ++t) {
        if (t + 1 < NT) stage(cur ^ 1, t + 1);
        const char* Ab = (const char*)(smem + cur*16384);
        const char* Bb = Ab + 8192;
        short8 af[4], bfr[4];
#pragma unroll
        for (int mi = 0; mi < 4; ++mi) {
            int r = wm*64 + mi*16 + lo;
            int ib = hi * 16;
            af[mi] = *(const short8*)(Ab + r*64 + (ib ^ ((r & 3) << 4)));
        }
#pragma unroll
        for (int ni = 0; ni < 4; ++ni) {
            int r = wn*64 + ni*16 + lo;
            int ib = hi * 16;
            bfr[ni] = *(const short8*)(Bb + r*64 + (ib ^ ((r & 3) << 4)));
        }
        __builtin_amdgcn_s_setprio(1);
#pragma unroll
        for (int mi = 0; mi < 4; ++mi)
#pragma unroll
            for (int ni = 0; ni < 4; ++ni)
                acc[mi][ni] = __builtin_amdgcn_mfma_f32_16x16x32_bf16(af[mi], bfr[ni], acc[mi][ni], 0, 0, 0);
        __builtin_amdgcn_s_setprio(0);
        __syncthreads();
        cur ^= 1;
    }

    if (MODE == 0) {
        // RoPE + scale + write [B,H,S,HD]
        bool fbf = (((const u16*)fcos)[0] == 0x3F80u);   // freqs dtype self-detect
        u16* outp = (u16*)Cout;
#pragma unroll
        for (int mi = 0; mi < 4; ++mi)
#pragma unroll
            for (int ni = 0; ni < 4; ++ni)
#pragma unroll
                for (int r = 0; r < 4; ++r) {
                    int gm = m0 + wm*64 + mi*16 + hi*4 + r;
                    int gc = n0 + wn*64 + ni*16 + lo;
                    float v  = acc[mi][ni][r];
                    float vp = __shfl_xor(v, 1);
                    int s = gm & (SS-1), d = gc & 63, i2 = d >> 1;
                    float c, sn;
                    if (fbf) { c = bf2f(((const u16*)fcos)[s*32 + i2]); sn = bf2f(((const u16*)fsin)[s*32 + i2]); }
                    else     { c = ((const float*)fcos)[s*32 + i2];     sn = ((const float*)fsin)[s*32 + i2]; }
                    float o = (gc & 1) ? (vp*sn + v*c) : (v*c - vp*sn);
                    o *= oscale;
                    int b = gm >> 11, h = gc >> 6;
                    outp[((((size_t)b*HH + h)*SS + s) << 6) + d] = f2bf(o);
                }
    } else if (MODE == 2) {
        // transpose per-wave 64x64 -> V^T [B,H,HD,S]
        __syncthreads();   // all waves done reading staging LDS
        u16* vs = (u16*)smem + w * (64*72);  // [64 d][72 s]
#pragma unroll
        for (int ni = 0; ni < 4; ++ni) {
            int d = ni*16 + lo;
#pragma unroll
            for (int mi = 0; mi < 4; ++mi)
#pragma unroll
                for (int rr = 0; rr < 2; ++rr) {
                    unsigned pk = (unsigned)f2bf(acc[mi][ni][2*rr]) | ((unsigned)f2bf(acc[mi][ni][2*rr+1]) << 16);
                    *(unsigned*)(vs + d*72 + mi*16 + hi*4 + rr*2) = pk;
                }
        }
        asm volatile("s_waitcnt lgkmcnt(0)" ::: "memory");
        int bq = (m0 + wm*64) >> 11;
        int s_base = (m0 + wm*64) & (SS-1);
        int h = (n0 + wn*64) >> 6;
        u16* outp = (u16*)Cout;
#pragma unroll
        for (int p = 0; p < 8; ++p) {
            int idx = p*64 + l;
            int row = idx >> 3, ch = idx & 7;
            short8 vv = *(const short8*)(vs + row*72 + ch*8);
            *(short8*)(outp + (((size_t)bq*HH + h)*64 + row)*SS + s_base + ch*8) = vv;
        }
    } else {
        bool isbf = tens_is_bf(mref);
#pragma unroll
        for (int mi = 0; mi < 4; ++mi)
#pragma unroll
            for (int ni = 0; ni < 4; ++ni)
#pragma unroll
                for (int r = 0; r < 4; ++r) {
                    int gm = m0 + wm*64 + mi*16 + hi*4 + r;
                    int gc = n0 + wn*64 + ni*16 + lo;
                    float v = acc[mi][ni][r];
                    if (isbf) ((u16*)Cout)[(size_t)gm*DD + gc] = f2bf(v);
                    else      ((float*)Cout)[(size_t)gm*DD + gc] = v;
                }
    }
}

// ---------- kernel 4: causal flash attention v3 (swapped 32x32 MFMA, in-register softmax) ----------
// Q,K: [B,H,S,64] bf16 (Q pre-scaled by 1/8) ; VT: [B,H,64,S] bf16 ; AO: [B,S,D] bf16
// Block: 4 waves x 32 q-rows = 128 q. Per phase (KVBLK=64):
//   S^T[kv][q] = mfma(Kfrag, Qfrag)  -> lane-pair owns a q-row -> in-lane softmax
//   P^T stays in-register via cvt_pk_bf16 + permlane32_swap
//   O^T[d][q] = mfma(VTfrag, P^Tfrag) -> m/l/rescale lane-local
__global__ __launch_bounds__(256) void attn(const u16* __restrict__ Q, const u16* __restrict__ K,
                                            const u16* __restrict__ VT, u16* __restrict__ AO) {
    __shared__ __align__(16) u16 Kl[2][64*64];   // 8KB per buffer: 64 kv-rows x 128B
    __shared__ __align__(16) u16 Vl[2][64*64];   // 8KB per buffer: 64 d-rows x 128B
    int bh = blockIdx.x;
    int qt = (gridDim.y - 1) - blockIdx.y;          // longest first
    int tid = threadIdx.x, w = tid >> 6, l = tid & 63;
    int l31 = l & 31, hi5 = l >> 5;
    const u16* Qb = Q  + (size_t)bh * SS * 64;
    const u16* Kb = K  + (size_t)bh * SS * 64;
    const u16* Vb = VT + (size_t)bh * 64 * SS;
    int q0w = qt*128 + w*32;                         // wave's first q-row
    int q   = q0w + l31;                             // this lane-pair's q-row

    // Q as B-operand fragments: qf[kc] = Q[q][kc*16 + hi5*8 .. +8]
    short8 qf[4];
#pragma unroll
    for (int kc = 0; kc < 4; ++kc)
        qf[kc] = *(const short8*)(Qb + (size_t)q*64 + kc*16 + hi5*8);

    f32x16 oacc[2] = {};     // O^T frags: col=q, rows d (dt*32 + pattern)
    float m_ = -1e30f, l_ = 0.f;

    auto stage = [&](int buf, int kt) {
        const char* Kt = (const char*)(Kb + (size_t)kt*64*64);
        const char* Vt = (const char*)Vb + (size_t)kt*128;
#pragma unroll
        for (int i = 0; i < 2; ++i) {
            int idx = i*256 + tid;
            int row = idx >> 3, inb = (idx & 7) * 16;   // 128B rows
            int sw = inb ^ ((row & 7) << 4);
            gload16(Kt + row*128 + sw,            (char*)Kl[buf] + (i*256 + (tid & ~63))*16);
            gload16(Vt + (size_t)row*(SS*2) + sw, (char*)Vl[buf] + (i*256 + (tid & ~63))*16);
        }
    };

    int nkt = 2*qt + 2;
    stage(0, 0);
    __syncthreads();
    int cur = 0;

    for (int kt = 0; kt < nkt; ++kt) {
        if (kt + 1 < nkt) stage(cur ^ 1, kt + 1);    // prefetch overlaps compute

        if (kt*64 <= q0w + 31) {                     // wave-uniform causal skip
            // ---- QK^T (swapped): sc[kvt] = S^T rows kvt*32.., cols q ----
            f32x16 sc[2] = {};
            __builtin_amdgcn_s_setprio(1);
#pragma unroll
            for (int kvt = 0; kvt < 2; ++kvt) {
                short8 kf[4];
#pragma unroll
                for (int kc = 0; kc < 4; ++kc) {
                    int row = kvt*32 + l31;
                    int ib = kc*32 + hi5*16;
                    kf[kc] = *(const short8*)((const char*)Kl[cur] + row*128 + (ib ^ ((row & 7) << 4)));
                }
#pragma unroll
                for (int kc = 0; kc < 4; ++kc)
                    sc[kvt] = __builtin_amdgcn_mfma_f32_32x32x16_bf16(kf[kc], qf[kc], sc[kvt], 0, 0, 0);
            }
            __builtin_amdgcn_s_setprio(0);

            // ---- mask (diagonal tiles only) ----
            if (kt*64 + 63 > q0w) {
#pragma unroll
                for (int kvt = 0; kvt < 2; ++kvt)
#pragma unroll
                    for (int rg = 0; rg < 16; ++rg) {
                        int kv = kt*64 + kvt*32 + (rg & 3) + 8*(rg >> 2) + 4*hi5;
                        if (kv > q) sc[kvt][rg] = -1e9f;
                    }
            }

            // ---- online softmax (lane-local q-row; partner lane is l^32) ----
            float mx = -1e30f;
#pragma unroll
            for (int kvt = 0; kvt < 2; ++kvt)
#pragma unroll
                for (int rg = 0; rg < 16; ++rg) mx = fmaxf(mx, sc[kvt][rg]);
            mx = fmaxf(mx, __shfl_xor(mx, 32));
            float mn = fmaxf(m_, mx);
            float al = __expf(m_ - mn);
            float rs = 0.f;
#pragma unroll
            for (int kvt = 0; kvt < 2; ++kvt)
#pragma unroll
                for (int rg = 0; rg < 16; ++rg) {
                    float p = __expf(sc[kvt][rg] - mn);
                    sc[kvt][rg] = p;
                    rs += p;
                }
            rs += __shfl_xor(rs, 32);
            m_ = mn;
            l_ = l_ * al + rs;
#pragma unroll
            for (int dt = 0; dt < 2; ++dt)
#pragma unroll
                for (int rg = 0; rg < 16; ++rg) oacc[dt][rg] *= al;

            // ---- P^T -> B-fragments in-register (cvt_pk + permlane32_swap) ----
            short8 pa[4];
#pragma unroll
            for (int kc = 0; kc < 4; ++kc) {
                const int kvt = kc >> 1;
                const int base = (kc & 1) * 8;
                unsigned A0 = cvtpk(sc[kvt][base + 0], sc[kvt][base + 1]);
                unsigned A1 = cvtpk(sc[kvt][base + 2], sc[kvt][base + 3]);
                unsigned B0 = cvtpk(sc[kvt][base + 4], sc[kvt][base + 5]);
                unsigned B1 = cvtpk(sc[kvt][base + 6], sc[kvt][base + 7]);
                asm("v_permlane32_swap_b32 %0, %1" : "+v"(A0), "+v"(B0));
                asm("v_permlane32_swap_b32 %0, %1" : "+v"(A1), "+v"(B1));
                u32x4 pk; pk[0] = A0; pk[1] = A1; pk[2] = B0; pk[3] = B1;
                pa[kc] = __builtin_bit_cast(short8, pk);
            }

            // ---- PV (transposed): oacc[dt] += VTfrag x P^T ----
            __builtin_amdgcn_s_setprio(1);
#pragma unroll
            for (int dt = 0; dt < 2; ++dt) {
                short8 vf[4];
#pragma unroll
                for (int kc = 0; kc < 4; ++kc) {
                    int row = dt*32 + l31;
                    int ib = kc*32 + hi5*16;
                    vf[kc] = *(const short8*)((const char*)Vl[cur] + row*128 + (ib ^ ((row & 7) << 4)));
                }
#pragma unroll
                for (int kc = 0; kc < 4; ++kc)
                    oacc[dt] = __builtin_amdgcn_mfma_f32_32x32x16_bf16(vf[kc], pa[kc], oacc[dt], 0, 0, 0);
            }
            __builtin_amdgcn_s_setprio(0);
        }

        __syncthreads();     // buffer handoff; drains prefetch vmcnt
        cur ^= 1;
    }

    // ---- epilogue: O[q][d] = oacc^T / l ----
    int b = bh >> 4, h = bh & 15;
    float inv = 1.0f / l_;
    u16* aor = AO + (size_t)(b*SS + q)*DD + h*64;
#pragma unroll
    for (int dt = 0; dt < 2; ++dt)
#pragma unroll
        for (int j = 0; j < 8; ++j) {
            int r0 = 2*j, r1 = 2*j + 1;
            int d = dt*32 + (r0 & 3) + 8*(r0 >> 2) + 4*hi5;
            unsigned pk = (unsigned)f2bf(oacc[dt][r0] * inv) | ((unsigned)f2bf(oacc[dt][r1] * inv) << 16);
            *(unsigned*)(aor + d) = pk;
        }
}

// ---------- launch ----------
extern "C" void kernel_launch(void* const* d_in, const int* in_sizes, int n_in,
                              void* d_out, int out_size, void* d_ws, size_t ws_size,
                              hipStream_t stream) {
    const void* x    = d_in[0];
    const void* fcos = d_in[1];
    const void* fsin = d_in[2];
    const u16*  mref = (const u16*)d_in[3];
    const void* wq   = d_in[4];
    const void* wk   = d_in[5];
    const void* wv   = d_in[6];
    const void* wo   = d_in[7];

    u16* ws = (u16*)d_ws;
    const size_t XB = (size_t)MM * DD;     // 8,388,608
    const size_t WT = (size_t)DD * DD;     // 1,048,576
    u16* xb  = ws;                 // x bf16 ; later aliased as attention output
    u16* wt  = ws + XB;            // 4 transposed weights
    u16* qb  = ws + XB + 4*WT;
    u16* kb  = qb + XB;
    u16* vtb = kb + XB;

    cvt_x<<<4096, 256, 0, stream>>>(x, xb, mref);
    trw<<<dim3(32, 32, 4), 256, 0, stream>>>(wq, wk, wv, wo, wt, mref);
    gemm128<0><<<dim3(64, 8), 256, 0, stream>>>(xb, wt,        qb,  fcos, fsin, mref, 0.125f);
    gemm128<0><<<dim3(64, 8), 256, 0, stream>>>(xb, wt + WT,   kb,  fcos, fsin, mref, 1.0f);
    gemm128<2><<<dim3(64, 8), 256, 0, stream>>>(xb, wt + 2*WT, vtb, fcos, fsin, mref, 1.0f);
    attn<<<dim3(64, 16), 256, 0, stream>>>(qb, kb, vtb, xb);   // AO aliases xb (safe: stream-ordered)
    gemm128<3><<<dim3(64, 8), 256, 0, stream>>>(xb, wt + 3*WT, d_out, fcos, fsin, mref, 1.0f);
}

// Round 13
// 188.497 us; speedup vs baseline: 1.0643x; 1.0339x over previous
//
#include <hip/hip_runtime.h>
#include <stdint.h>

typedef short short8 __attribute__((ext_vector_type(8)));
typedef float f32x4 __attribute__((ext_vector_type(4)));
typedef float f32x16 __attribute__((ext_vector_type(16)));
typedef unsigned int u32x4 __attribute__((ext_vector_type(4)));
typedef float float4e __attribute__((ext_vector_type(4)));
typedef unsigned short u16;

#define BB 4
#define SS 2048
#define DD 1024
#define HH 16
#define MM (BB*SS)   // 8192

// ---------- helpers ----------
__device__ __forceinline__ u16 f2bf(float f) {
    unsigned u = __float_as_uint(f);
    u += 0x7FFFu + ((u >> 16) & 1u);   // RTN-even
    return (u16)(u >> 16);
}
__device__ __forceinline__ float bf2f(u16 h) {
    return __uint_as_float(((unsigned)h) << 16);
}
__device__ __forceinline__ unsigned cvtpk(float a, float b) {
    unsigned r;
    asm("v_cvt_pk_bf16_f32 %0, %1, %2" : "=v"(r) : "v"(a), "v"(b));
    return r;
}
// async global->LDS, 16B per lane. dst must be wave-uniform base (HW adds lane*16).
__device__ __forceinline__ void gload16(const void* g, void* l) {
    __builtin_amdgcn_global_load_lds(
        (const __attribute__((address_space(1))) unsigned int*)(uintptr_t)g,
        (__attribute__((address_space(3))) unsigned int*)(unsigned)(uintptr_t)l,
        16, 0, 0);
}
__device__ __forceinline__ bool tens_is_bf(const u16* mref) { return mref[1] == 0xCE6Eu; }

// ---------- kernel 1: x -> bf16 ----------
__global__ __launch_bounds__(256) void cvt_x(const void* xin, u16* xb, const u16* mref) {
    bool isbf = tens_is_bf(mref);
    size_t i = (size_t)blockIdx.x * 256 + threadIdx.x;   // handles 8 elements
    if (isbf) {
        ((u32x4*)xb)[i] = ((const u32x4*)xin)[i];
    } else {
        const float4e* src = (const float4e*)xin;
        float4e a = src[2*i], b = src[2*i+1];
        u32x4 o;
        o[0] = (unsigned)f2bf(a[0]) | ((unsigned)f2bf(a[1]) << 16);
        o[1] = (unsigned)f2bf(a[2]) | ((unsigned)f2bf(a[3]) << 16);
        o[2] = (unsigned)f2bf(b[0]) | ((unsigned)f2bf(b[1]) << 16);
        o[3] = (unsigned)f2bf(b[2]) | ((unsigned)f2bf(b[3]) << 16);
        ((u32x4*)xb)[i] = o;
    }
}

// ---------- kernel 2: weights -> bf16 W^T [N][K] ----------
__global__ __launch_bounds__(256) void trw(const void* w0, const void* w1, const void* w2, const void* w3,
                                           u16* wt, const u16* mref) {
    bool isbf = tens_is_bf(mref);
    const void* w = (blockIdx.z == 0) ? w0 : (blockIdx.z == 1) ? w1 : (blockIdx.z == 2) ? w2 : w3;
    u16* out = wt + (size_t)blockIdx.z * (DD*DD);
    __shared__ float t[32][33];
    int tx = threadIdx.x & 31, ty = threadIdx.x >> 5;    // ty 0..7
    int n0 = blockIdx.x * 32, k0 = blockIdx.y * 32;
#pragma unroll
    for (int i = 0; i < 4; ++i) {
        int k = k0 + ty*4 + i;
        float v = isbf ? bf2f(((const u16*)w)[(size_t)k*DD + n0 + tx])
                       : ((const float*)w)[(size_t)k*DD + n0 + tx];
        t[ty*4 + i][tx] = v;
    }
    __syncthreads();
#pragma unroll
    for (int i = 0; i < 4; ++i)
        out[(size_t)(n0 + ty*4 + i)*DD + k0 + tx] = f2bf(t[tx][ty*4 + i]);
}

// ---------- kernel 3: 128x128 GEMM, A[M][K] bf16 row-major, Bt[N][K] bf16 row-major ----------
// MODE 1: merged QKV via blockIdx.z (z=0 Q RoPE*0.125, z=1 K RoPE, z=2 V^T transpose).
//         Per-block work/tile/swizzle identical to the 3 separate R3 launches; z slowest in
//         dispatch order => same ordering, minus two inter-launch drain boundaries.
// MODE 3: final projection, out f32 or bf16 [M][D] per runtime flag.
template<int MODE>
__global__ __launch_bounds__(256) void gemm128(const u16* __restrict__ A, const u16* __restrict__ wt,
                                               u16* outQ, u16* outK, u16* outVT, void* Cout,
                                               const void* fcos, const void* fsin,
                                               const u16* mref) {
    constexpr int SMEMB = (MODE == 1) ? 36864 : 32768;
    __shared__ __align__(16) unsigned char smem[SMEMB];
    int tid = threadIdx.x;
    int w = tid >> 6, l = tid & 63, lo = l & 15, hi = l >> 4;
    int wm = w >> 1, wn = w & 1;
    int m0 = blockIdx.x * 128, n0 = blockIdx.y * 128;
    int wi = (MODE == 1) ? (int)blockIdx.z : 3;
    const u16* Bt = (MODE == 1) ? wt + (size_t)wi * (DD*DD) : wt;

    f32x4 acc[4][4] = {};

    auto stage = [&](int buf, int t) {
        int k0 = t * 32;
#pragma unroll
        for (int i = 0; i < 2; ++i) {
            int o = (i*256 + tid) * 16;          // 0..8191 linear byte offset in tile
            int row = o >> 6, inb = o & 63;      // 64B per row (32 bf16)
            int sw  = inb ^ ((row & 3) << 4);    // XOR swizzle, both-sides
            gload16((const char*)A + ((size_t)(m0 + row)*DD + k0)*2 + sw,
                    smem + buf*16384 + (i*256 + (tid & ~63))*16);
            gload16((const char*)Bt + ((size_t)(n0 + row)*DD + k0)*2 + sw,
                    smem + buf*16384 + 8192 + (i*256 + (tid & ~63))*16);
        }
    };

    stage(0, 0);
    __syncthreads();
    int cur = 0;
    const int NT = DD / 32;   // 32
    for (int t = 0; t < NT; ++t) {
        if (t + 1 < NT) stage(cur ^ 1, t + 1);
        const char* Ab = (const char*)(smem + cur*16384);
        const char* Bb = Ab + 8192;
        short8 af[4], bfr[4];
#pragma unroll
        for (int mi = 0; mi < 4; ++mi) {
            int r = wm*64 + mi*16 + lo;
            int ib = hi * 16;
            af[mi] = *(const short8*)(Ab + r*64 + (ib ^ ((r & 3) << 4)));
        }
#pragma unroll
        for (int ni = 0; ni < 4; ++ni) {
            int r = wn*64 + ni*16 + lo;
            int ib = hi * 16;
            bfr[ni] = *(const short8*)(Bb + r*64 + (ib ^ ((r & 3) << 4)));
        }
        __builtin_amdgcn_s_setprio(1);
#pragma unroll
        for (int mi = 0; mi < 4; ++mi)
#pragma unroll
            for (int ni = 0; ni < 4; ++ni)
                acc[mi][ni] = __builtin_amdgcn_mfma_f32_16x16x32_bf16(af[mi], bfr[ni], acc[mi][ni], 0, 0, 0);
        __builtin_amdgcn_s_setprio(0);
        __syncthreads();
        cur ^= 1;
    }

    if (MODE == 1 && wi == 2) {
        // V: transpose per-wave 64x64 -> V^T [B,H,HD,S]
        __syncthreads();   // all waves done reading staging LDS
        u16* vs = (u16*)smem + w * (64*72);  // [64 d][72 s]
#pragma unroll
        for (int ni = 0; ni < 4; ++ni) {
            int d = ni*16 + lo;
#pragma unroll
            for (int mi = 0; mi < 4; ++mi)
#pragma unroll
                for (int rr = 0; rr < 2; ++rr) {
                    unsigned pk = (unsigned)f2bf(acc[mi][ni][2*rr]) | ((unsigned)f2bf(acc[mi][ni][2*rr+1]) << 16);
                    *(unsigned*)(vs + d*72 + mi*16 + hi*4 + rr*2) = pk;
                }
        }
        asm volatile("s_waitcnt lgkmcnt(0)" ::: "memory");
        int bq = (m0 + wm*64) >> 11;
        int s_base = (m0 + wm*64) & (SS-1);
        int h = (n0 + wn*64) >> 6;
#pragma unroll
        for (int p = 0; p < 8; ++p) {
            int idx = p*64 + l;
            int row = idx >> 3, ch = idx & 7;
            short8 vv = *(const short8*)(vs + row*72 + ch*8);
            *(short8*)(outVT + (((size_t)bq*HH + h)*64 + row)*SS + s_base + ch*8) = vv;
        }
    } else if (MODE == 1) {
        // Q/K: RoPE + (Q-only) scale + write [B,H,S,HD]
        bool fbf = (((const u16*)fcos)[0] == 0x3F80u);   // freqs dtype self-detect
        u16* outp = wi ? outK : outQ;
        float oscale = wi ? 1.0f : 0.125f;
#pragma unroll
        for (int mi = 0; mi < 4; ++mi)
#pragma unroll
            for (int ni = 0; ni < 4; ++ni)
#pragma unroll
                for (int r = 0; r < 4; ++r) {
                    int gm = m0 + wm*64 + mi*16 + hi*4 + r;
                    int gc = n0 + wn*64 + ni*16 + lo;
                    float v  = acc[mi][ni][r];
                    float vp = __shfl_xor(v, 1);
                    int s = gm & (SS-1), d = gc & 63, i2 = d >> 1;
                    float c, sn;
                    if (fbf) { c = bf2f(((const u16*)fcos)[s*32 + i2]); sn = bf2f(((const u16*)fsin)[s*32 + i2]); }
                    else     { c = ((const float*)fcos)[s*32 + i2];     sn = ((const float*)fsin)[s*32 + i2]; }
                    float o = (gc & 1) ? (vp*sn + v*c) : (v*c - vp*sn);
                    o *= oscale;
                    int b = gm >> 11, h = gc >> 6;
                    outp[((((size_t)b*HH + h)*SS + s) << 6) + d] = f2bf(o);
                }
    } else {
        bool isbf = tens_is_bf(mref);
#pragma unroll
        for (int mi = 0; mi < 4; ++mi)
#pragma unroll
            for (int ni = 0; ni < 4; ++ni)
#pragma unroll
                for (int r = 0; r < 4; ++r) {
                    int gm = m0 + wm*64 + mi*16 + hi*4 + r;
                    int gc = n0 + wn*64 + ni*16 + lo;
                    float v = acc[mi][ni][r];
                    if (isbf) ((u16*)Cout)[(size_t)gm*DD + gc] = f2bf(v);
                    else      ((float*)Cout)[(size_t)gm*DD + gc] = v;
                }
    }
}

// ---------- kernel 4: causal flash attention v3 (measured best, byte-identical to R10/R12) ----------
__global__ __launch_bounds__(256) void attn(const u16* __restrict__ Q, const u16* __restrict__ K,
                                            const u16* __restrict__ VT, u16* __restrict__ AO) {
    __shared__ __align__(16) u16 Kl[2][64*64];   // 8KB per buffer: 64 kv-rows x 128B
    __shared__ __align__(16) u16 Vl[2][64*64];   // 8KB per buffer: 64 d-rows x 128B
    int bh = blockIdx.x;
    int qt = (gridDim.y - 1) - blockIdx.y;          // longest first
    int tid = threadIdx.x, w = tid >> 6, l = tid & 63;
    int l31 = l & 31, hi5 = l >> 5;
    const u16* Qb = Q  + (size_t)bh * SS * 64;
    const u16* Kb = K  + (size_t)bh * SS * 64;
    const u16* Vb = VT + (size_t)bh * 64 * SS;
    int q0w = qt*128 + w*32;                         // wave's first q-row
    int q   = q0w + l31;                             // this lane-pair's q-row

    // Q as B-operand fragments: qf[kc] = Q[q][kc*16 + hi5*8 .. +8]
    short8 qf[4];
#pragma unroll
    for (int kc = 0; kc < 4; ++kc)
        qf[kc] = *(const short8*)(Qb + (size_t)q*64 + kc*16 + hi5*8);

    f32x16 oacc[2] = {};     // O^T frags: col=q, rows d (dt*32 + pattern)
    float m_ = -1e30f, l_ = 0.f;

    auto stage = [&](int buf, int kt) {
        const char* Kt = (const char*)(Kb + (size_t)kt*64*64);
        const char* Vt = (const char*)Vb + (size_t)kt*128;
#pragma unroll
        for (int i = 0; i < 2; ++i) {
            int idx = i*256 + tid;
            int row = idx >> 3, inb = (idx & 7) * 16;   // 128B rows
            int sw = inb ^ ((row & 7) << 4);
            gload16(Kt + row*128 + sw,            (char*)Kl[buf] + (i*256 + (tid & ~63))*16);
            gload16(Vt + (size_t)row*(SS*2) + sw, (char*)Vl[buf] + (i*256 + (tid & ~63))*16);
        }
    };

    int nkt = 2*qt + 2;
    stage(0, 0);
    __syncthreads();
    int cur = 0;

    for (int kt = 0; kt < nkt; ++kt) {
        if (kt + 1 < nkt) stage(cur ^ 1, kt + 1);    // prefetch overlaps compute

        if (kt*64 <= q0w + 31) {                     // wave-uniform causal skip
            // ---- QK^T (swapped): sc[kvt] = S^T rows kvt*32.., cols q ----
            f32x16 sc[2] = {};
            __builtin_amdgcn_s_setprio(1);
#pragma unroll
            for (int kvt = 0; kvt < 2; ++kvt) {
                short8 kf[4];
#pragma unroll
                for (int kc = 0; kc < 4; ++kc) {
                    int row = kvt*32 + l31;
                    int ib = kc*32 + hi5*16;
                    kf[kc] = *(const short8*)((const char*)Kl[cur] + row*128 + (ib ^ ((row & 7) << 4)));
                }
#pragma unroll
                for (int kc = 0; kc < 4; ++kc)
                    sc[kvt] = __builtin_amdgcn_mfma_f32_32x32x16_bf16(kf[kc], qf[kc], sc[kvt], 0, 0, 0);
            }
            __builtin_amdgcn_s_setprio(0);

            // ---- mask (diagonal tiles only) ----
            if (kt*64 + 63 > q0w) {
#pragma unroll
                for (int kvt = 0; kvt < 2; ++kvt)
#pragma unroll
                    for (int rg = 0; rg < 16; ++rg) {
                        int kv = kt*64 + kvt*32 + (rg & 3) + 8*(rg >> 2) + 4*hi5;
                        if (kv > q) sc[kvt][rg] = -1e9f;
                    }
            }

            // ---- online softmax (lane-local q-row; partner lane is l^32) ----
            float mx = -1e30f;
#pragma unroll
            for (int kvt = 0; kvt < 2; ++kvt)
#pragma unroll
                for (int rg = 0; rg < 16; ++rg) mx = fmaxf(mx, sc[kvt][rg]);
            mx = fmaxf(mx, __shfl_xor(mx, 32));
            float mn = fmaxf(m_, mx);
            float al = __expf(m_ - mn);
            float rs = 0.f;
#pragma unroll
            for (int kvt = 0; kvt < 2; ++kvt)
#pragma unroll
                for (int rg = 0; rg < 16; ++rg) {
                    float p = __expf(sc[kvt][rg] - mn);
                    sc[kvt][rg] = p;
                    rs += p;
                }
            rs += __shfl_xor(rs, 32);
            m_ = mn;
            l_ = l_ * al + rs;
#pragma unroll
            for (int dt = 0; dt < 2; ++dt)
#pragma unroll
                for (int rg = 0; rg < 16; ++rg) oacc[dt][rg] *= al;

            // ---- P^T -> B-fragments in-register (cvt_pk + permlane32_swap) ----
            short8 pa[4];
#pragma unroll
            for (int kc = 0; kc < 4; ++kc) {
                const int kvt = kc >> 1;
                const int base = (kc & 1) * 8;
                unsigned A0 = cvtpk(sc[kvt][base + 0], sc[kvt][base + 1]);
                unsigned A1 = cvtpk(sc[kvt][base + 2], sc[kvt][base + 3]);
                unsigned B0 = cvtpk(sc[kvt][base + 4], sc[kvt][base + 5]);
                unsigned B1 = cvtpk(sc[kvt][base + 6], sc[kvt][base + 7]);
                asm("v_permlane32_swap_b32 %0, %1" : "+v"(A0), "+v"(B0));
                asm("v_permlane32_swap_b32 %0, %1" : "+v"(A1), "+v"(B1));
                u32x4 pk; pk[0] = A0; pk[1] = A1; pk[2] = B0; pk[3] = B1;
                pa[kc] = __builtin_bit_cast(short8, pk);
            }

            // ---- PV (transposed): oacc[dt] += VTfrag x P^T ----
            __builtin_amdgcn_s_setprio(1);
#pragma unroll
            for (int dt = 0; dt < 2; ++dt) {
                short8 vf[4];
#pragma unroll
                for (int kc = 0; kc < 4; ++kc) {
                    int row = dt*32 + l31;
                    int ib = kc*32 + hi5*16;
                    vf[kc] = *(const short8*)((const char*)Vl[cur] + row*128 + (ib ^ ((row & 7) << 4)));
                }
#pragma unroll
                for (int kc = 0; kc < 4; ++kc)
                    oacc[dt] = __builtin_amdgcn_mfma_f32_32x32x16_bf16(vf[kc], pa[kc], oacc[dt], 0, 0, 0);
            }
            __builtin_amdgcn_s_setprio(0);
        }

        __syncthreads();     // buffer handoff; drains prefetch vmcnt
        cur ^= 1;
    }

    // ---- epilogue: O[q][d] = oacc^T / l ----
    int b = bh >> 4, h = bh & 15;
    float inv = 1.0f / l_;
    u16* aor = AO + (size_t)(b*SS + q)*DD + h*64;
#pragma unroll
    for (int dt = 0; dt < 2; ++dt)
#pragma unroll
        for (int j = 0; j < 8; ++j) {
            int r0 = 2*j, r1 = 2*j + 1;
            int d = dt*32 + (r0 & 3) + 8*(r0 >> 2) + 4*hi5;
            unsigned pk = (unsigned)f2bf(oacc[dt][r0] * inv) | ((unsigned)f2bf(oacc[dt][r1] * inv) << 16);
            *(unsigned*)(aor + d) = pk;
        }
}

// ---------- launch ----------
extern "C" void kernel_launch(void* const* d_in, const int* in_sizes, int n_in,
                              void* d_out, int out_size, void* d_ws, size_t ws_size,
                              hipStream_t stream) {
    const void* x    = d_in[0];
    const void* fcos = d_in[1];
    const void* fsin = d_in[2];
    const u16*  mref = (const u16*)d_in[3];
    const void* wq   = d_in[4];
    const void* wk   = d_in[5];
    const void* wv   = d_in[6];
    const void* wo   = d_in[7];

    u16* ws = (u16*)d_ws;
    const size_t XB = (size_t)MM * DD;     // 8,388,608
    const size_t WT = (size_t)DD * DD;     // 1,048,576
    u16* xb  = ws;                 // x bf16 ; later aliased as attention output
    u16* wt  = ws + XB;            // 4 transposed weights (wq,wk,wv,wo contiguous)
    u16* qb  = ws + XB + 4*WT;
    u16* kb  = qb + XB;
    u16* vtb = kb + XB;

    cvt_x<<<4096, 256, 0, stream>>>(x, xb, mref);
    trw<<<dim3(32, 32, 4), 256, 0, stream>>>(wq, wk, wv, wo, wt, mref);
    // merged QKV: identical 128x128 tiles, z selects weight (z slowest => same order as 3 launches,
    // minus two inter-launch drain boundaries)
    gemm128<1><<<dim3(64, 8, 3), 256, 0, stream>>>(xb, wt, qb, kb, vtb, nullptr, fcos, fsin, mref);
    attn<<<dim3(64, 16), 256, 0, stream>>>(qb, kb, vtb, xb);   // AO aliases xb (safe: stream-ordered)
    gemm128<3><<<dim3(64, 8), 256, 0, stream>>>(xb, wt + 3*WT, nullptr, nullptr, nullptr, d_out, fcos, fsin, mref);
}

// Round 14
// 186.034 us; speedup vs baseline: 1.0784x; 1.0132x over previous
//
#include <hip/hip_runtime.h>
#include <stdint.h>

typedef short short8 __attribute__((ext_vector_type(8)));
typedef float f32x4 __attribute__((ext_vector_type(4)));
typedef float f32x16 __attribute__((ext_vector_type(16)));
typedef unsigned int u32x4 __attribute__((ext_vector_type(4)));
typedef float float4e __attribute__((ext_vector_type(4)));
typedef unsigned short u16;

#define BB 4
#define SS 2048
#define DD 1024
#define HH 16
#define MM (BB*SS)   // 8192

// ---------- helpers ----------
__device__ __forceinline__ u16 f2bf(float f) {
    unsigned u = __float_as_uint(f);
    u += 0x7FFFu + ((u >> 16) & 1u);   // RTN-even
    return (u16)(u >> 16);
}
__device__ __forceinline__ float bf2f(u16 h) {
    return __uint_as_float(((unsigned)h) << 16);
}
__device__ __forceinline__ unsigned cvtpk(float a, float b) {
    unsigned r;
    asm("v_cvt_pk_bf16_f32 %0, %1, %2" : "=v"(r) : "v"(a), "v"(b));
    return r;
}
// async global->LDS, 16B per lane. dst must be wave-uniform base (HW adds lane*16).
__device__ __forceinline__ void gload16(const void* g, void* l) {
    __builtin_amdgcn_global_load_lds(
        (const __attribute__((address_space(1))) unsigned int*)(uintptr_t)g,
        (__attribute__((address_space(3))) unsigned int*)(unsigned)(uintptr_t)l,
        16, 0, 0);
}
__device__ __forceinline__ bool tens_is_bf(const u16* mref) { return mref[1] == 0xCE6Eu; }

// ---------- kernel 1: merged prep = {x -> bf16} + {weights -> bf16 W^T [N][K]} ----------
// Blocks 0..4095: cvt path (8 elems/thread). Blocks 4096..8191: trw path (one 32x32 tile).
// Merging removes one inter-launch drain boundary; per-block work identical to the
// measured R13 cvt_x / trw kernels.
__global__ __launch_bounds__(256) void prep(const void* xin, u16* xb,
                                            const void* w0, const void* w1, const void* w2, const void* w3,
                                            u16* wt, const u16* mref) {
    __shared__ float t[32][33];
    bool isbf = tens_is_bf(mref);
    int bid = blockIdx.x;
    if (bid < 4096) {
        size_t i = (size_t)bid * 256 + threadIdx.x;   // handles 8 elements
        if (isbf) {
            ((u32x4*)xb)[i] = ((const u32x4*)xin)[i];
        } else {
            const float4e* src = (const float4e*)xin;
            float4e a = src[2*i], b = src[2*i+1];
            u32x4 o;
            o[0] = (unsigned)f2bf(a[0]) | ((unsigned)f2bf(a[1]) << 16);
            o[1] = (unsigned)f2bf(a[2]) | ((unsigned)f2bf(a[3]) << 16);
            o[2] = (unsigned)f2bf(b[0]) | ((unsigned)f2bf(b[1]) << 16);
            o[3] = (unsigned)f2bf(b[2]) | ((unsigned)f2bf(b[3]) << 16);
            ((u32x4*)xb)[i] = o;
        }
    } else {
        int b2 = bid - 4096;
        int zi = b2 >> 10;                   // 0..3 weight index
        int rem = b2 & 1023;
        int bx = rem & 31, by = rem >> 5;    // (32 n-tiles, 32 k-tiles)
        const void* w = (zi == 0) ? w0 : (zi == 1) ? w1 : (zi == 2) ? w2 : w3;
        u16* out = wt + (size_t)zi * (DD*DD);
        int tx = threadIdx.x & 31, ty = threadIdx.x >> 5;    // ty 0..7
        int n0 = bx * 32, k0 = by * 32;
#pragma unroll
        for (int i = 0; i < 4; ++i) {
            int k = k0 + ty*4 + i;
            float v = isbf ? bf2f(((const u16*)w)[(size_t)k*DD + n0 + tx])
                           : ((const float*)w)[(size_t)k*DD + n0 + tx];
            t[ty*4 + i][tx] = v;
        }
        __syncthreads();
#pragma unroll
        for (int i = 0; i < 4; ++i)
            out[(size_t)(n0 + ty*4 + i)*DD + k0 + tx] = f2bf(t[tx][ty*4 + i]);
    }
}

// ---------- kernel 3: 128x128 GEMM, A[M][K] bf16 row-major, Bt[N][K] bf16 row-major ----------
// MODE 1: merged QKV via blockIdx.z (z=0 Q RoPE*0.125, z=1 K RoPE, z=2 V^T transpose).
//         Per-block work/tile/swizzle identical to the 3 separate R3 launches; z slowest in
//         dispatch order => same ordering, minus two inter-launch drain boundaries.
// MODE 3: final projection, out f32 or bf16 [M][D] per runtime flag.
template<int MODE>
__global__ __launch_bounds__(256) void gemm128(const u16* __restrict__ A, const u16* __restrict__ wt,
                                               u16* outQ, u16* outK, u16* outVT, void* Cout,
                                               const void* fcos, const void* fsin,
                                               const u16* mref) {
    constexpr int SMEMB = (MODE == 1) ? 36864 : 32768;
    __shared__ __align__(16) unsigned char smem[SMEMB];
    int tid = threadIdx.x;
    int w = tid >> 6, l = tid & 63, lo = l & 15, hi = l >> 4;
    int wm = w >> 1, wn = w & 1;
    int m0 = blockIdx.x * 128, n0 = blockIdx.y * 128;
    int wi = (MODE == 1) ? (int)blockIdx.z : 3;
    const u16* Bt = (MODE == 1) ? wt + (size_t)wi * (DD*DD) : wt;

    f32x4 acc[4][4] = {};

    auto stage = [&](int buf, int t) {
        int k0 = t * 32;
#pragma unroll
        for (int i = 0; i < 2; ++i) {
            int o = (i*256 + tid) * 16;          // 0..8191 linear byte offset in tile
            int row = o >> 6, inb = o & 63;      // 64B per row (32 bf16)
            int sw  = inb ^ ((row & 3) << 4);    // XOR swizzle, both-sides
            gload16((const char*)A + ((size_t)(m0 + row)*DD + k0)*2 + sw,
                    smem + buf*16384 + (i*256 + (tid & ~63))*16);
            gload16((const char*)Bt + ((size_t)(n0 + row)*DD + k0)*2 + sw,
                    smem + buf*16384 + 8192 + (i*256 + (tid & ~63))*16);
        }
    };

    stage(0, 0);
    __syncthreads();
    int cur = 0;
    const int NT = DD / 32;   // 32
    for (int t = 0; t < NT; ++t) {
        if (t + 1 < NT) stage(cur ^ 1, t + 1);
        const char* Ab = (const char*)(smem + cur*16384);
        const char* Bb = Ab + 8192;
        short8 af[4], bfr[4];
#pragma unroll
        for (int mi = 0; mi < 4; ++mi) {
            int r = wm*64 + mi*16 + lo;
            int ib = hi * 16;
            af[mi] = *(const short8*)(Ab + r*64 + (ib ^ ((r & 3) << 4)));
        }
#pragma unroll
        for (int ni = 0; ni < 4; ++ni) {
            int r = wn*64 + ni*16 + lo;
            int ib = hi * 16;
            bfr[ni] = *(const short8*)(Bb + r*64 + (ib ^ ((r & 3) << 4)));
        }
        __builtin_amdgcn_s_setprio(1);
#pragma unroll
        for (int mi = 0; mi < 4; ++mi)
#pragma unroll
            for (int ni = 0; ni < 4; ++ni)
                acc[mi][ni] = __builtin_amdgcn_mfma_f32_16x16x32_bf16(af[mi], bfr[ni], acc[mi][ni], 0, 0, 0);
        __builtin_amdgcn_s_setprio(0);
        __syncthreads();
        cur ^= 1;
    }

    if (MODE == 1 && wi == 2) {
        // V: transpose per-wave 64x64 -> V^T [B,H,HD,S]
        __syncthreads();   // all waves done reading staging LDS
        u16* vs = (u16*)smem + w * (64*72);  // [64 d][72 s]
#pragma unroll
        for (int ni = 0; ni < 4; ++ni) {
            int d = ni*16 + lo;
#pragma unroll
            for (int mi = 0; mi < 4; ++mi)
#pragma unroll
                for (int rr = 0; rr < 2; ++rr) {
                    unsigned pk = (unsigned)f2bf(acc[mi][ni][2*rr]) | ((unsigned)f2bf(acc[mi][ni][2*rr+1]) << 16);
                    *(unsigned*)(vs + d*72 + mi*16 + hi*4 + rr*2) = pk;
                }
        }
        asm volatile("s_waitcnt lgkmcnt(0)" ::: "memory");
        int bq = (m0 + wm*64) >> 11;
        int s_base = (m0 + wm*64) & (SS-1);
        int h = (n0 + wn*64) >> 6;
#pragma unroll
        for (int p = 0; p < 8; ++p) {
            int idx = p*64 + l;
            int row = idx >> 3, ch = idx & 7;
            short8 vv = *(const short8*)(vs + row*72 + ch*8);
            *(short8*)(outVT + (((size_t)bq*HH + h)*64 + row)*SS + s_base + ch*8) = vv;
        }
    } else if (MODE == 1) {
        // Q/K: RoPE + (Q-only) scale + write [B,H,S,HD]
        bool fbf = (((const u16*)fcos)[0] == 0x3F80u);   // freqs dtype self-detect
        u16* outp = wi ? outK : outQ;
        float oscale = wi ? 1.0f : 0.125f;
#pragma unroll
        for (int mi = 0; mi < 4; ++mi)
#pragma unroll
            for (int ni = 0; ni < 4; ++ni)
#pragma unroll
                for (int r = 0; r < 4; ++r) {
                    int gm = m0 + wm*64 + mi*16 + hi*4 + r;
                    int gc = n0 + wn*64 + ni*16 + lo;
                    float v  = acc[mi][ni][r];
                    float vp = __shfl_xor(v, 1);
                    int s = gm & (SS-1), d = gc & 63, i2 = d >> 1;
                    float c, sn;
                    if (fbf) { c = bf2f(((const u16*)fcos)[s*32 + i2]); sn = bf2f(((const u16*)fsin)[s*32 + i2]); }
                    else     { c = ((const float*)fcos)[s*32 + i2];     sn = ((const float*)fsin)[s*32 + i2]; }
                    float o = (gc & 1) ? (vp*sn + v*c) : (v*c - vp*sn);
                    o *= oscale;
                    int b = gm >> 11, h = gc >> 6;
                    outp[((((size_t)b*HH + h)*SS + s) << 6) + d] = f2bf(o);
                }
    } else {
        bool isbf = tens_is_bf(mref);
#pragma unroll
        for (int mi = 0; mi < 4; ++mi)
#pragma unroll
            for (int ni = 0; ni < 4; ++ni)
#pragma unroll
                for (int r = 0; r < 4; ++r) {
                    int gm = m0 + wm*64 + mi*16 + hi*4 + r;
                    int gc = n0 + wn*64 + ni*16 + lo;
                    float v = acc[mi][ni][r];
                    if (isbf) ((u16*)Cout)[(size_t)gm*DD + gc] = f2bf(v);
                    else      ((float*)Cout)[(size_t)gm*DD + gc] = v;
                }
    }
}

// ---------- kernel 4: causal flash attention v3 (measured best, byte-identical to R10/R12/R13) ----------
__global__ __launch_bounds__(256) void attn(const u16* __restrict__ Q, const u16* __restrict__ K,
                                            const u16* __restrict__ VT, u16* __restrict__ AO) {
    __shared__ __align__(16) u16 Kl[2][64*64];   // 8KB per buffer: 64 kv-rows x 128B
    __shared__ __align__(16) u16 Vl[2][64*64];   // 8KB per buffer: 64 d-rows x 128B
    int bh = blockIdx.x;
    int qt = (gridDim.y - 1) - blockIdx.y;          // longest first
    int tid = threadIdx.x, w = tid >> 6, l = tid & 63;
    int l31 = l & 31, hi5 = l >> 5;
    const u16* Qb = Q  + (size_t)bh * SS * 64;
    const u16* Kb = K  + (size_t)bh * SS * 64;
    const u16* Vb = VT + (size_t)bh * 64 * SS;
    int q0w = qt*128 + w*32;                         // wave's first q-row
    int q   = q0w + l31;                             // this lane-pair's q-row

    // Q as B-operand fragments: qf[kc] = Q[q][kc*16 + hi5*8 .. +8]
    short8 qf[4];
#pragma unroll
    for (int kc = 0; kc < 4; ++kc)
        qf[kc] = *(const short8*)(Qb + (size_t)q*64 + kc*16 + hi5*8);

    f32x16 oacc[2] = {};     // O^T frags: col=q, rows d (dt*32 + pattern)
    float m_ = -1e30f, l_ = 0.f;

    auto stage = [&](int buf, int kt) {
        const char* Kt = (const char*)(Kb + (size_t)kt*64*64);
        const char* Vt = (const char*)Vb + (size_t)kt*128;
#pragma unroll
        for (int i = 0; i < 2; ++i) {
            int idx = i*256 + tid;
            int row = idx >> 3, inb = (idx & 7) * 16;   // 128B rows
            int sw = inb ^ ((row & 7) << 4);
            gload16(Kt + row*128 + sw,            (char*)Kl[buf] + (i*256 + (tid & ~63))*16);
            gload16(Vt + (size_t)row*(SS*2) + sw, (char*)Vl[buf] + (i*256 + (tid & ~63))*16);
        }
    };

    int nkt = 2*qt + 2;
    stage(0, 0);
    __syncthreads();
    int cur = 0;

    for (int kt = 0; kt < nkt; ++kt) {
        if (kt + 1 < nkt) stage(cur ^ 1, kt + 1);    // prefetch overlaps compute

        if (kt*64 <= q0w + 31) {                     // wave-uniform causal skip
            // ---- QK^T (swapped): sc[kvt] = S^T rows kvt*32.., cols q ----
            f32x16 sc[2] = {};
            __builtin_amdgcn_s_setprio(1);
#pragma unroll
            for (int kvt = 0; kvt < 2; ++kvt) {
                short8 kf[4];
#pragma unroll
                for (int kc = 0; kc < 4; ++kc) {
                    int row = kvt*32 + l31;
                    int ib = kc*32 + hi5*16;
                    kf[kc] = *(const short8*)((const char*)Kl[cur] + row*128 + (ib ^ ((row & 7) << 4)));
                }
#pragma unroll
                for (int kc = 0; kc < 4; ++kc)
                    sc[kvt] = __builtin_amdgcn_mfma_f32_32x32x16_bf16(kf[kc], qf[kc], sc[kvt], 0, 0, 0);
            }
            __builtin_amdgcn_s_setprio(0);

            // ---- mask (diagonal tiles only) ----
            if (kt*64 + 63 > q0w) {
#pragma unroll
                for (int kvt = 0; kvt < 2; ++kvt)
#pragma unroll
                    for (int rg = 0; rg < 16; ++rg) {
                        int kv = kt*64 + kvt*32 + (rg & 3) + 8*(rg >> 2) + 4*hi5;
                        if (kv > q) sc[kvt][rg] = -1e9f;
                    }
            }

            // ---- online softmax (lane-local q-row; partner lane is l^32) ----
            float mx = -1e30f;
#pragma unroll
            for (int kvt = 0; kvt < 2; ++kvt)
#pragma unroll
                for (int rg = 0; rg < 16; ++rg) mx = fmaxf(mx, sc[kvt][rg]);
            mx = fmaxf(mx, __shfl_xor(mx, 32));
            float mn = fmaxf(m_, mx);
            float al = __expf(m_ - mn);
            float rs = 0.f;
#pragma unroll
            for (int kvt = 0; kvt < 2; ++kvt)
#pragma unroll
                for (int rg = 0; rg < 16; ++rg) {
                    float p = __expf(sc[kvt][rg] - mn);
                    sc[kvt][rg] = p;
                    rs += p;
                }
            rs += __shfl_xor(rs, 32);
            m_ = mn;
            l_ = l_ * al + rs;
#pragma unroll
            for (int dt = 0; dt < 2; ++dt)
#pragma unroll
                for (int rg = 0; rg < 16; ++rg) oacc[dt][rg] *= al;

            // ---- P^T -> B-fragments in-register (cvt_pk + permlane32_swap) ----
            short8 pa[4];
#pragma unroll
            for (int kc = 0; kc < 4; ++kc) {
                const int kvt = kc >> 1;
                const int base = (kc & 1) * 8;
                unsigned A0 = cvtpk(sc[kvt][base + 0], sc[kvt][base + 1]);
                unsigned A1 = cvtpk(sc[kvt][base + 2], sc[kvt][base + 3]);
                unsigned B0 = cvtpk(sc[kvt][base + 4], sc[kvt][base + 5]);
                unsigned B1 = cvtpk(sc[kvt][base + 6], sc[kvt][base + 7]);
                asm("v_permlane32_swap_b32 %0, %1" : "+v"(A0), "+v"(B0));
                asm("v_permlane32_swap_b32 %0, %1" : "+v"(A1), "+v"(B1));
                u32x4 pk; pk[0] = A0; pk[1] = A1; pk[2] = B0; pk[3] = B1;
                pa[kc] = __builtin_bit_cast(short8, pk);
            }

            // ---- PV (transposed): oacc[dt] += VTfrag x P^T ----
            __builtin_amdgcn_s_setprio(1);
#pragma unroll
            for (int dt = 0; dt < 2; ++dt) {
                short8 vf[4];
#pragma unroll
                for (int kc = 0; kc < 4; ++kc) {
                    int row = dt*32 + l31;
                    int ib = kc*32 + hi5*16;
                    vf[kc] = *(const short8*)((const char*)Vl[cur] + row*128 + (ib ^ ((row & 7) << 4)));
                }
#pragma unroll
                for (int kc = 0; kc < 4; ++kc)
                    oacc[dt] = __builtin_amdgcn_mfma_f32_32x32x16_bf16(vf[kc], pa[kc], oacc[dt], 0, 0, 0);
            }
            __builtin_amdgcn_s_setprio(0);
        }

        __syncthreads();     // buffer handoff; drains prefetch vmcnt
        cur ^= 1;
    }

    // ---- epilogue: O[q][d] = oacc^T / l ----
    int b = bh >> 4, h = bh & 15;
    float inv = 1.0f / l_;
    u16* aor = AO + (size_t)(b*SS + q)*DD + h*64;
#pragma unroll
    for (int dt = 0; dt < 2; ++dt)
#pragma unroll
        for (int j = 0; j < 8; ++j) {
            int r0 = 2*j, r1 = 2*j + 1;
            int d = dt*32 + (r0 & 3) + 8*(r0 >> 2) + 4*hi5;
            unsigned pk = (unsigned)f2bf(oacc[dt][r0] * inv) | ((unsigned)f2bf(oacc[dt][r1] * inv) << 16);
            *(unsigned*)(aor + d) = pk;
        }
}

// ---------- launch ----------
extern "C" void kernel_launch(void* const* d_in, const int* in_sizes, int n_in,
                              void* d_out, int out_size, void* d_ws, size_t ws_size,
                              hipStream_t stream) {
    const void* x    = d_in[0];
    const void* fcos = d_in[1];
    const void* fsin = d_in[2];
    const u16*  mref = (const u16*)d_in[3];
    const void* wq   = d_in[4];
    const void* wk   = d_in[5];
    const void* wv   = d_in[6];
    const void* wo   = d_in[7];

    u16* ws = (u16*)d_ws;
    const size_t XB = (size_t)MM * DD;     // 8,388,608
    const size_t WT = (size_t)DD * DD;     // 1,048,576
    u16* xb  = ws;                 // x bf16 ; later aliased as attention output
    u16* wt  = ws + XB;            // 4 transposed weights (wq,wk,wv,wo contiguous)
    u16* qb  = ws + XB + 4*WT;
    u16* kb  = qb + XB;
    u16* vtb = kb + XB;

    // merged converts: blocks 0..4095 = x->bf16, 4096..8191 = weight transposes
    prep<<<8192, 256, 0, stream>>>(x, xb, wq, wk, wv, wo, wt, mref);
    // merged QKV: identical 128x128 tiles, z selects weight (z slowest => same order as 3 launches,
    // minus two inter-launch drain boundaries)
    gemm128<1><<<dim3(64, 8, 3), 256, 0, stream>>>(xb, wt, qb, kb, vtb, nullptr, fcos, fsin, mref);
    attn<<<dim3(64, 16), 256, 0, stream>>>(qb, kb, vtb, xb);   // AO aliases xb (safe: stream-ordered)
    gemm128<3><<<dim3(64, 8), 256, 0, stream>>>(xb, wt + 3*WT, nullptr, nullptr, nullptr, d_out, fcos, fsin, mref);
}